// Round 3
// baseline (1207.268 us; speedup 1.0000x reference)
//
#include <hip/hip_runtime.h>
#include <math.h>

#define NROWS 131072
#define BM 64
#define NBLK (NROWS / BM)        // 2048
#define NB 10
#define PPF 29
#define NRAW 928
#define NPAD 1024
#define HID 512
#define THREADS 512

typedef _Float16 half8 __attribute__((ext_vector_type(8)));
typedef _Float16 half4v __attribute__((ext_vector_type(4)));
typedef float f32x4 __attribute__((ext_vector_type(4)));

// ws layout: W2T fp16 [NPAD][HID] at 0 (1 MB); W1T fp16 [HID][32] after it (32 KB)
#define W1T_OFF (NPAD * HID * 2)

// LDS: union region (h fp16 [64 rows][stride 1040 B] = 66560 B; params f32
// [16][stride 936 dwords] = 59904 B reuses it), + sb2.
#define HSTR 1040
#define PSTR 936
#define SMEM_BYTES (BM * HSTR)   // 66560

__global__ __launch_bounds__(256) void prep_w2(const float* __restrict__ W2,
                                               _Float16* __restrict__ W2T) {
    __shared__ float tile[32][33];
    const int kt = blockIdx.x >> 5;      // 0..15 (k tile)
    const int nt = blockIdx.x & 31;      // 0..31 (n tile)
    const int t = threadIdx.x;
    const int j = t & 31;                // n_local
    const int i0 = t >> 5;               // 0..7
    #pragma unroll
    for (int q = 0; q < 4; ++q) {
        int i = i0 + q * 8;              // k_local
        int n = nt * 32 + j;
        float v = 0.f;
        if (n < NRAW) v = W2[(size_t)(kt * 32 + i) * NRAW + n];
        tile[i][j] = v;
    }
    __syncthreads();
    const int n_l = t >> 3;              // 0..31
    const int k_l = (t & 7) * 4;         // 0..28
    half4v o;
    o[0] = (_Float16)tile[k_l + 0][n_l];
    o[1] = (_Float16)tile[k_l + 1][n_l];
    o[2] = (_Float16)tile[k_l + 2][n_l];
    o[3] = (_Float16)tile[k_l + 3][n_l];
    *(half4v*)&W2T[(size_t)(nt * 32 + n_l) * HID + kt * 32 + k_l] = o;
}

__global__ __launch_bounds__(256) void prep_w1(const float* __restrict__ W1,
                                               _Float16* __restrict__ W1T) {
    int idx = blockIdx.x * 256 + threadIdx.x;   // 0..16383
    int n = idx >> 5, k = idx & 31;
    W1T[n * 32 + k] = (_Float16)W1[k * HID + n];
}

__device__ __forceinline__ float softplusf(float v) {
    return fmaxf(v, 0.f) + log1pf(expf(-fabsf(v)));
}

__device__ __forceinline__ void rqs_one(const float* p, float xv, float& yo,
                                        float& lad_o, float& ot_o) {
    const float SCALE = 0.04419417382415922f;  // 1/sqrt(512)
    float uw[NB];
    #pragma unroll
    for (int j = 0; j < NB; ++j) uw[j] = p[j] * SCALE;
    float mw = uw[0];
    #pragma unroll
    for (int j = 1; j < NB; ++j) mw = fmaxf(mw, uw[j]);
    float sw = 0.f;
    #pragma unroll
    for (int j = 0; j < NB; ++j) { uw[j] = expf(uw[j] - mw); sw += uw[j]; }
    float invw = 1.f / sw;
    float cw[NB + 1];
    cw[0] = -1.f;
    float cum = 0.f;
    #pragma unroll
    for (int j = 0; j < NB; ++j) {
        cum += 0.001f + 0.99f * uw[j] * invw;
        cw[j + 1] = 2.f * cum - 1.f;
    }
    cw[NB] = 1.f;

    float uh[NB];
    #pragma unroll
    for (int j = 0; j < NB; ++j) uh[j] = p[NB + j] * SCALE;
    float mh = uh[0];
    #pragma unroll
    for (int j = 1; j < NB; ++j) mh = fmaxf(mh, uh[j]);
    float sh = 0.f;
    #pragma unroll
    for (int j = 0; j < NB; ++j) { uh[j] = expf(uh[j] - mh); sh += uh[j]; }
    float invh = 1.f / sh;
    float ch[NB + 1];
    ch[0] = -1.f;
    float cumh = 0.f;
    #pragma unroll
    for (int j = 0; j < NB; ++j) {
        cumh += 0.001f + 0.99f * uh[j] * invh;
        ch[j + 1] = 2.f * cumh - 1.f;
    }
    ch[NB] = 1.f;

    float dv[NB + 1];
    dv[0] = 1.0f;
    dv[NB] = 1.0f;
    #pragma unroll
    for (int j = 0; j < NB - 1; ++j) dv[j + 1] = 0.001f + softplusf(p[2 * NB + j]);

    float xc = fminf(fmaxf(xv, -1.f), 1.f);
    int idx = 0;
    #pragma unroll
    for (int j = 1; j <= NB - 1; ++j) idx += (xc >= cw[j]) ? 1 : 0;
    float in_cw = cw[0], cwn = cw[1];
    float in_ch = ch[0], chn = ch[1];
    float dk = dv[0], dk1 = dv[1];
    #pragma unroll
    for (int j = 1; j <= NB - 1; ++j) {
        bool cnd = (idx >= j);
        in_cw = cnd ? cw[j] : in_cw;
        cwn   = cnd ? cw[j + 1] : cwn;
        in_ch = cnd ? ch[j] : in_ch;
        chn   = cnd ? ch[j + 1] : chn;
        dk    = cnd ? dv[j] : dk;
        dk1   = cnd ? dv[j + 1] : dk1;
    }
    float in_w  = cwn - in_cw;
    float in_h  = chn - in_ch;
    float delta = in_h / in_w;
    float th    = (xc - in_cw) / in_w;
    float t1m   = th * (1.f - th);
    float th2   = th * th;
    float numer = in_h * (delta * th2 + dk * t1m);
    float denom = delta + (dk + dk1 - 2.f * delta) * t1m;
    float y     = in_ch + numer / denom;
    float omt   = 1.f - th;
    float dnum  = delta * delta * (dk1 * th2 + 2.f * delta * t1m + dk * omt * omt);
    float lad   = logf(dnum) - 2.f * logf(denom);

    bool inside = (xv >= -1.f) && (xv <= 1.f);
    yo = inside ? y : xv;
    lad_o = inside ? lad : 0.f;
    float dd = xv - yo;
    ot_o = dd * dd;
}

template<int NPAIR>
__device__ __forceinline__ void gemm2_run(f32x4 (&acc)[32], const half8 (&afk)[16],
                                          const char* w2b) {
    #pragma unroll
    for (int jp = 0; jp < NPAIR; ++jp) {
        const char* p0 = w2b + (size_t)jp * 32768;
        const char* p1 = p0 + 16384;
        #pragma unroll
        for (int ks = 0; ks < 16; ++ks) {
            half8 bf0 = *(const half8*)(p0 + ks * 64);
            half8 bf1 = *(const half8*)(p1 + ks * 64);
            acc[2 * jp]     = __builtin_amdgcn_mfma_f32_16x16x32_f16(afk[ks], bf0, acc[2 * jp], 0, 0, 0);
            acc[2 * jp + 1] = __builtin_amdgcn_mfma_f32_16x16x32_f16(afk[ks], bf1, acc[2 * jp + 1], 0, 0, 0);
        }
    }
}

__global__ __launch_bounds__(THREADS, 2) void flow_main(
    const float* __restrict__ x,
    const float* __restrict__ b1,
    const float* __restrict__ b2,
    const _Float16* __restrict__ W2T,
    const _Float16* __restrict__ W1T,
    float* __restrict__ out,
    float* __restrict__ lad_out,
    float* __restrict__ ot_out)
{
    __shared__ __align__(16) char smem[SMEM_BYTES];  // h (fp16) then params (f32)
    __shared__ float sb2[NRAW];
    const int tid = threadIdx.x;
    const int w   = tid >> 6;      // wave 0..7
    const int l   = tid & 63;
    const int l15 = l & 15;
    const int g   = l >> 4;        // k-group 0..3
    const int row0 = blockIdx.x * BM;
    const int mt1 = w >> 1;        // m-tile this wave owns
    const int nh  = w & 1;         // n-half this wave owns

    // ---- identity copy x -> out (even cols overwritten by spline later) ----
    {
        const float4* xv = (const float4*)(x + (size_t)row0 * 64);
        float4* ov = (float4*)(out + (size_t)row0 * 64);
        ov[tid] = xv[tid];
        ov[tid + 512] = xv[tid + 512];
    }
    sb2[tid] = b2[tid];
    if (tid < NRAW - 512) sb2[tid + 512] = b2[tid + 512];

    // ---- GEMM1: h = relu(ident @ W1 + b1); h -> LDS, padded stride 1040B ----
    {
        const int nbase = nh * 256;
        half8 a1;
        {
            const float4* xr = (const float4*)(x + (size_t)(row0 + mt1 * 16 + l15) * 64 + g * 16);
            float4 q0 = xr[0], q1 = xr[1], q2 = xr[2], q3 = xr[3];
            a1[0] = (_Float16)q0.y; a1[1] = (_Float16)q0.w;
            a1[2] = (_Float16)q1.y; a1[3] = (_Float16)q1.w;
            a1[4] = (_Float16)q2.y; a1[5] = (_Float16)q2.w;
            a1[6] = (_Float16)q3.y; a1[7] = (_Float16)q3.w;
        }
        #pragma unroll
        for (int j = 0; j < 16; ++j) {
            int n = nbase + j * 16 + l15;
            half8 bf = *(const half8*)((const char*)W1T + (size_t)n * 64 + g * 16);
            f32x4 c = {0.f, 0.f, 0.f, 0.f};
            c = __builtin_amdgcn_mfma_f32_16x16x32_f16(a1, bf, c, 0, 0, 0);
            float bias = b1[n];
            #pragma unroll
            for (int r = 0; r < 4; ++r) {
                float hv = fmaxf(c[r] + bias, 0.f);
                *(_Float16*)(smem + (mt1 * 16 + g * 4 + r) * HSTR + n * 2) = (_Float16)hv;
            }
        }
    }
    __syncthreads();

    // ---- A-fragments for this wave's m-tile: 16 ds_read_b128, linear addr ----
    half8 afk[16];
    {
        const char* abase = smem + (mt1 * 16 + l15) * HSTR + g * 16;
        #pragma unroll
        for (int ks = 0; ks < 16; ++ks)
            afk[ks] = *(const half8*)(abase + ks * 64);
    }

    // ---- GEMM2: barrier-free, B-frags direct from L2 ----
    f32x4 acc[32];
    #pragma unroll
    for (int i = 0; i < 32; ++i) acc[i] = (f32x4){0.f, 0.f, 0.f, 0.f};

    const char* w2b = (const char*)W2T + ((size_t)(nh * 512 + l15) * (HID * 2) + g * 16);
    if (nh == 0) gemm2_run<16>(acc, afk, w2b);   // n tiles 0..31
    else         gemm2_run<13>(acc, afk, w2b);   // n tiles 0..25 (928-n skip)

    // ---- epilogue: 4 passes (16 rows each): params transpose + spline ----
    #pragma unroll
    for (int q = 0; q < 4; ++q) {
        __syncthreads();   // previous pass reads done / h reads done (q==0)
        if (mt1 == q) {
            #pragma unroll
            for (int j2 = 0; j2 < 32; ++j2) {
                int n = nh * 512 + j2 * 16 + l15;
                if (nh == 0 || j2 < 26) {
                    if (n < NRAW) {
                        #pragma unroll
                        for (int r = 0; r < 4; ++r)
                            *(float*)(smem + ((g * 4 + r) * PSTR + n) * 4) = acc[j2][r];
                    }
                }
            }
        }
        __syncthreads();

        int row_l = tid >> 5;
        int f = tid & 31;
        int grow = row0 + q * 16 + row_l;
        float p[PPF];
        #pragma unroll
        for (int jj = 0; jj < PPF; ++jj)
            p[jj] = *(const float*)(smem + (row_l * PSTR + f * PPF + jj) * 4)
                    + sb2[f * PPF + jj];
        float xv = x[(size_t)grow * 64 + 2 * f];
        float yo, lo, oo;
        rqs_one(p, xv, yo, lo, oo);
        out[(size_t)grow * 64 + 2 * f] = yo;
        float ladp = lo, otp = oo;
        #pragma unroll
        for (int m = 1; m < 32; m <<= 1) {
            ladp += __shfl_xor(ladp, m);
            otp  += __shfl_xor(otp, m);
        }
        if ((tid & 31) == 0) {
            lad_out[grow] = ladp;
            ot_out[grow]  = otp;
        }
    }
}

extern "C" void kernel_launch(void* const* d_in, const int* in_sizes, int n_in,
                              void* d_out, int out_size, void* d_ws, size_t ws_size,
                              hipStream_t stream) {
    const float* x  = (const float*)d_in[0];
    const float* W1 = (const float*)d_in[1];
    const float* b1 = (const float*)d_in[2];
    const float* W2 = (const float*)d_in[3];
    const float* b2 = (const float*)d_in[4];
    float* out = (float*)d_out;
    float* lad = out + (size_t)NROWS * 64;
    float* otc = lad + NROWS;

    char* wsb = (char*)d_ws;
    _Float16* W2T = (_Float16*)wsb;
    _Float16* W1T = (_Float16*)(wsb + W1T_OFF);

    hipLaunchKernelGGL(prep_w2, dim3(512), dim3(256), 0, stream, W2, W2T);
    hipLaunchKernelGGL(prep_w1, dim3(64), dim3(256), 0, stream, W1, W1T);
    hipLaunchKernelGGL(flow_main, dim3(NBLK), dim3(THREADS), 0, stream,
                       x, b1, b2, W2T, W1T, out, lad, otc);
}

// Round 6
// 529.432 us; speedup vs baseline: 2.2803x; 2.2803x over previous
//
#include <hip/hip_runtime.h>
#include <math.h>

#define NROWS 131072
#define BM 64
#define NBLK (NROWS / BM)        // 2048
#define NB 10
#define PPF 29
#define NRAW 928
#define NPAD 1024
#define HID 512
#define THREADS 1024

typedef _Float16 half8 __attribute__((ext_vector_type(8)));
typedef float f32x4 __attribute__((ext_vector_type(4)));

// ws: W2S swizzled-k-tiled [16 ks][64 KB] = 1 MB at 0; W1T fp16 [512][32] at 1 MB.
#define W1T_OFF (1 << 20)

// LDS: h fp16 [64 rows][stride 1040 B] = 66560 B at 0; B chunk 64 KB at 66560.
// Epilogue params f32 [32][PSTR=937] = 119936 B overlays the whole region.
#define HSTR 1040
#define LDS_B 66560
#define SMEM_BYTES (66560 + 65536)   // 132096
#define PSTR 937

__device__ __forceinline__ void async_copy16(const void* g, void* l) {
    __builtin_amdgcn_global_load_lds(
        (const __attribute__((address_space(1))) unsigned int*)g,
        (__attribute__((address_space(3))) unsigned int*)l, 16, 0, 0);
}

// ---- prep: W2 [512 k][928 n] f32  ->  W2S fp16, k-tiled + slot-swizzled ----
// element (k, n): ks=k>>5, g=(k>>3)&3, j=k&7
// byte addr = ks*65536 + n*64 + ((g ^ ((n>>1)&3))<<4) + j*2 ; n>=928 zero-pad
__global__ __launch_bounds__(256) void prep_w2(const float* __restrict__ W2,
                                               _Float16* __restrict__ W2S) {
    int flat = blockIdx.x * 256 + threadIdx.x;   // 0..65535 = (ks*4+g)*1024 + n
    int n  = flat & 1023;
    int kg = flat >> 10;
    int ks = kg >> 2, g = kg & 3;
    half8 o;
    #pragma unroll
    for (int j = 0; j < 8; ++j) {
        int k = ks * 32 + g * 8 + j;
        float v = (n < NRAW) ? W2[(size_t)k * NRAW + n] : 0.f;
        o[j] = (_Float16)v;
    }
    size_t addr = (size_t)ks * 65536 + (size_t)n * 64 + ((g ^ ((n >> 1) & 3)) << 4);
    *(half8*)((char*)W2S + addr) = o;
}

__global__ __launch_bounds__(256) void prep_w1(const float* __restrict__ W1,
                                               _Float16* __restrict__ W1T) {
    int idx = blockIdx.x * 256 + threadIdx.x;   // 0..16383
    int n = idx >> 5, k = idx & 31;
    W1T[n * 32 + k] = (_Float16)W1[k * HID + n];
}

__device__ __forceinline__ float softplusf(float v) {
    return fmaxf(v, 0.f) + log1pf(expf(-fabsf(v)));
}

__global__ __launch_bounds__(THREADS, 4) void flow_main(
    const float* __restrict__ x,
    const float* __restrict__ b1,
    const float* __restrict__ b2,
    const _Float16* __restrict__ W2S,
    const _Float16* __restrict__ W1T,
    float* __restrict__ out,
    float* __restrict__ lad_out,
    float* __restrict__ ot_out)
{
    __shared__ __align__(16) char smem[SMEM_BYTES];
    __shared__ float sb2[NRAW];
    const int tid = threadIdx.x;
    const int w   = tid >> 6;       // wave 0..15
    const int l   = tid & 63;
    const int l15 = l & 15;
    const int g   = l >> 4;         // k-group 0..3
    const int wr  = w >> 3;         // row-half 0..1 (rows wr*32..+31)
    const int wc  = w & 7;          // n-slice 0..7 (cols wc*128..+127)
    const int row0 = blockIdx.x * BM;

    // ---- issue B chunk-0 DMA immediately (GEMM1 covers its latency) ----
    {
        const char* gsrc0 = (const char*)W2S + (size_t)(w * 4096) + (size_t)l * 16;
        char* ldst = smem + LDS_B + w * 4096;
        #pragma unroll
        for (int i = 0; i < 4; ++i)
            async_copy16(gsrc0 + i * 1024, ldst + i * 1024);
    }

    // ---- identity copy x -> out (even cols overwritten by spline later) ----
    // 1024 threads x one float4 = 4096 floats = the block's 64x64 tile exactly.
    {
        const float4* xv = (const float4*)(x + (size_t)row0 * 64);
        float4* ov = (float4*)(out + (size_t)row0 * 64);
        ov[tid] = xv[tid];
    }
    if (tid < NRAW) sb2[tid] = b2[tid];

    // ---- GEMM1: h = relu(ident @ W1 + b1) -> LDS  (wave w: hid cols w*32..+31) ----
    {
        half8 a1[4];
        #pragma unroll
        for (int mt1 = 0; mt1 < 4; ++mt1) {
            const float4* xr = (const float4*)(x + (size_t)(row0 + mt1 * 16 + l15) * 64 + g * 16);
            float4 q0 = xr[0], q1 = xr[1], q2 = xr[2], q3 = xr[3];
            half8 a;
            a[0] = (_Float16)q0.y; a[1] = (_Float16)q0.w;
            a[2] = (_Float16)q1.y; a[3] = (_Float16)q1.w;
            a[4] = (_Float16)q2.y; a[5] = (_Float16)q2.w;
            a[6] = (_Float16)q3.y; a[7] = (_Float16)q3.w;
            a1[mt1] = a;
        }
        #pragma unroll
        for (int nt = 0; nt < 2; ++nt) {
            int n1 = w * 32 + nt * 16 + l15;
            half8 bf = *(const half8*)((const char*)W1T + (size_t)n1 * 64 + g * 16);
            float bias = b1[n1];
            #pragma unroll
            for (int mt1 = 0; mt1 < 4; ++mt1) {
                f32x4 c = {0.f, 0.f, 0.f, 0.f};
                c = __builtin_amdgcn_mfma_f32_16x16x32_f16(a1[mt1], bf, c, 0, 0, 0);
                #pragma unroll
                for (int r = 0; r < 4; ++r) {
                    float hv = fmaxf(c[r] + bias, 0.f);
                    *(_Float16*)(smem + (mt1 * 16 + g * 4 + r) * HSTR + n1 * 2) = (_Float16)hv;
                }
            }
        }
    }
    __syncthreads();   // h ready; chunk 0 landed (compiler drains vmcnt here)

    // ---- GEMM2 main loop: 16 ksteps, single-buffer B, 2 barriers/kstep ----
    f32x4 acc[2][8];
    #pragma unroll
    for (int mt = 0; mt < 2; ++mt)
        #pragma unroll
        for (int j = 0; j < 8; ++j) acc[mt][j] = (f32x4){0.f, 0.f, 0.f, 0.f};

    const int hbase = (wr * 32 + l15) * HSTR + g * 16;          // + mt*16640 + ks*64
    const int n0 = wc * 128 + l15;
    const int bbase = LDS_B + n0 * 64 + ((g ^ ((n0 >> 1) & 3)) << 4);  // + j*1024
    const char* gsrc = (const char*)W2S + 65536 + (size_t)(w * 4096) + (size_t)l * 16;
    char* ldst = smem + LDS_B + w * 4096;

    for (int ks = 0; ks < 16; ++ks) {
        half8 a0 = *(const half8*)(smem + hbase + ks * 64);
        half8 a1 = *(const half8*)(smem + hbase + 16640 + ks * 64);
        half8 bf[8];
        #pragma unroll
        for (int j = 0; j < 8; ++j)
            if (wc < 7 || j < 2) bf[j] = *(const half8*)(smem + bbase + j * 1024);
        __syncthreads();                    // all waves done reading chunk ks
        if (ks < 15) {
            #pragma unroll
            for (int i = 0; i < 4; ++i)
                async_copy16(gsrc + i * 1024, ldst + i * 1024);
            gsrc += 65536;
        }
        #pragma unroll
        for (int j = 0; j < 8; ++j) {
            if (wc < 7 || j < 2) {
                acc[0][j] = __builtin_amdgcn_mfma_f32_16x16x32_f16(a0, bf[j], acc[0][j], 0, 0, 0);
                acc[1][j] = __builtin_amdgcn_mfma_f32_16x16x32_f16(a1, bf[j], acc[1][j], 0, 0, 0);
            }
        }
        __syncthreads();                    // chunk ks+1 fully in LDS
    }

    // ---- epilogue: 2 passes of 32 rows: params -> LDS, fused spline ----
    const float SCALE = 0.04419417382415922f;   // 1/sqrt(512)
    #pragma unroll
    for (int pass = 0; pass < 2; ++pass) {
        __syncthreads();
        if (wr == pass) {
            #pragma unroll
            for (int mt = 0; mt < 2; ++mt)
                #pragma unroll
                for (int j = 0; j < 8; ++j) {
                    int n = wc * 128 + j * 16 + l15;
                    if (n < NRAW) {
                        #pragma unroll
                        for (int r = 0; r < 4; ++r)
                            *(float*)(smem + ((mt * 16 + g * 4 + r) * PSTR + n) * 4) = acc[mt][j][r];
                    }
                }
        }
        __syncthreads();

        // spline: 1024 threads = 32 rows x 32 features
        const int row_l = tid >> 5;
        const int f = tid & 31;
        const int grow = row0 + pass * 32 + row_l;
        const char* pb = smem + ((size_t)row_l * PSTR + (size_t)f * PPF) * 4;
        const float* bp = sb2 + f * PPF;

        // widths
        float uw[NB];
        #pragma unroll
        for (int j = 0; j < NB; ++j)
            uw[j] = (*(const float*)(pb + j * 4) + bp[j]) * SCALE;
        float mw = uw[0];
        #pragma unroll
        for (int j = 1; j < NB; ++j) mw = fmaxf(mw, uw[j]);
        float sw = 0.f;
        #pragma unroll
        for (int j = 0; j < NB; ++j) { uw[j] = expf(uw[j] - mw); sw += uw[j]; }
        float invw = 1.f / sw;
        float cw[NB + 1];
        cw[0] = -1.f;
        float cum = 0.f;
        #pragma unroll
        for (int j = 0; j < NB; ++j) {
            cum += 0.001f + 0.99f * uw[j] * invw;
            cw[j + 1] = 2.f * cum - 1.f;
        }
        cw[NB] = 1.f;

        // heights (reuse uw regs)
        #pragma unroll
        for (int j = 0; j < NB; ++j)
            uw[j] = (*(const float*)(pb + (NB + j) * 4) + bp[NB + j]) * SCALE;
        float mh = uw[0];
        #pragma unroll
        for (int j = 1; j < NB; ++j) mh = fmaxf(mh, uw[j]);
        float sh = 0.f;
        #pragma unroll
        for (int j = 0; j < NB; ++j) { uw[j] = expf(uw[j] - mh); sh += uw[j]; }
        float invh = 1.f / sh;
        float ch[NB + 1];
        ch[0] = -1.f;
        float cumh = 0.f;
        #pragma unroll
        for (int j = 0; j < NB; ++j) {
            cumh += 0.001f + 0.99f * uw[j] * invh;
            ch[j + 1] = 2.f * cumh - 1.f;
        }
        ch[NB] = 1.f;

        // derivatives
        float dv[NB + 1];
        dv[0] = 1.0f;
        dv[NB] = 1.0f;
        #pragma unroll
        for (int j = 0; j < NB - 1; ++j)
            dv[j + 1] = 0.001f + softplusf(*(const float*)(pb + (2 * NB + j) * 4) + bp[2 * NB + j]);

        const float xv = x[(size_t)grow * 64 + 2 * f];
        float xc = fminf(fmaxf(xv, -1.f), 1.f);
        int idx = 0;
        #pragma unroll
        for (int j = 1; j <= NB - 1; ++j) idx += (xc >= cw[j]) ? 1 : 0;
        float in_cw = cw[0], cwn = cw[1];
        float in_ch = ch[0], chn = ch[1];
        float dk = dv[0], dk1 = dv[1];
        #pragma unroll
        for (int j = 1; j <= NB - 1; ++j) {
            bool cnd = (idx >= j);
            in_cw = cnd ? cw[j] : in_cw;
            cwn   = cnd ? cw[j + 1] : cwn;
            in_ch = cnd ? ch[j] : in_ch;
            chn   = cnd ? ch[j + 1] : chn;
            dk    = cnd ? dv[j] : dk;
            dk1   = cnd ? dv[j + 1] : dk1;
        }
        float in_w  = cwn - in_cw;
        float in_h  = chn - in_ch;
        float delta = in_h / in_w;
        float th    = (xc - in_cw) / in_w;
        float t1m   = th * (1.f - th);
        float th2   = th * th;
        float numer = in_h * (delta * th2 + dk * t1m);
        float denom = delta + (dk + dk1 - 2.f * delta) * t1m;
        float y     = in_ch + numer / denom;
        float omt   = 1.f - th;
        float dnum  = delta * delta * (dk1 * th2 + 2.f * delta * t1m + dk * omt * omt);
        float lad   = logf(dnum) - 2.f * logf(denom);

        bool inside = (xv >= -1.f) && (xv <= 1.f);
        float yo = inside ? y : xv;
        out[(size_t)grow * 64 + 2 * f] = yo;
        float ladp = inside ? lad : 0.f;
        float dd = xv - yo;
        float otp = dd * dd;

        #pragma unroll
        for (int m = 1; m < 32; m <<= 1) {
            ladp += __shfl_xor(ladp, m);
            otp  += __shfl_xor(otp, m);
        }
        if ((tid & 31) == 0) {
            lad_out[grow] = ladp;
            ot_out[grow]  = otp;
        }
    }
}

extern "C" void kernel_launch(void* const* d_in, const int* in_sizes, int n_in,
                              void* d_out, int out_size, void* d_ws, size_t ws_size,
                              hipStream_t stream) {
    const float* x  = (const float*)d_in[0];
    const float* W1 = (const float*)d_in[1];
    const float* b1 = (const float*)d_in[2];
    const float* W2 = (const float*)d_in[3];
    const float* b2 = (const float*)d_in[4];
    float* out = (float*)d_out;
    float* lad = out + (size_t)NROWS * 64;
    float* otc = lad + NROWS;

    char* wsb = (char*)d_ws;
    _Float16* W2S = (_Float16*)wsb;
    _Float16* W1T = (_Float16*)(wsb + W1T_OFF);

    hipLaunchKernelGGL(prep_w2, dim3(256), dim3(256), 0, stream, W2, W2S);
    hipLaunchKernelGGL(prep_w1, dim3(64), dim3(256), 0, stream, W1, W1T);
    hipLaunchKernelGGL(flow_main, dim3(NBLK), dim3(THREADS), 0, stream,
                       x, b1, b2, W2S, W1T, out, lad, otc);
}

// Round 7
// 478.034 us; speedup vs baseline: 2.5255x; 1.1075x over previous
//
#include <hip/hip_runtime.h>
#include <math.h>

#define M 131072
#define BM 128
#define NB 10
#define PPF 29
#define HID 512
#define N2 1024            // padded param cols: 32 features * 32
#define BN 256             // cols per block -> 8 features
#define NBN 4              // n-blocks
#define THREADS 512
#define NKS 16             // 512 / 32

typedef _Float16 half8 __attribute__((ext_vector_type(8)));
typedef float f32x4 __attribute__((ext_vector_type(4)));

// ---- workspace layout (6 MB total) ----
#define W2P_OFF 0                  // fp16 [16 ks][4 nblk][16 KB]  = 1 MB
#define W1T_OFF (1 << 20)          // fp16 [512 hid][32 k] = 32 KB
#define LADP_OFF (2 << 20)         // f32 [4][M] = 2 MB
#define OTP_OFF  (4 << 20)         // f32 [4][M] = 2 MB

// ---- LDS layout (flow_main) ----
#define STG  0                     // 16 KB B stage
#define WSCR 16384                 // 16 KB wave-private A scratch (8 x 2 KB)
#define OVR  0                     // epilogue overlay [64][268] f32 = 68608 B
#define SB1  68608                 // b1 f32 (2048 B)
#define SB2  70656                 // b2 slice f32 (928 B)
#define SMEM_BYTES 71584
#define PSTR 268

__device__ __forceinline__ void async_copy16(const void* g, void* l) {
    __builtin_amdgcn_global_load_lds(
        (const __attribute__((address_space(1))) unsigned int*)g,
        (__attribute__((address_space(3))) unsigned int*)l, 16, 0, 0);
}

__device__ __forceinline__ unsigned pkh(float a, float b) {
    union { _Float16 h[2]; unsigned u; } v;
    v.h[0] = (_Float16)a; v.h[1] = (_Float16)b;
    return v.u;
}

// ---- prep: W2 [512][928] f32 -> W2P fp16, feature-padded (n'=f*32+p),
//      k-tiled [ks][nblk][col_l*64 + slot*16 + j*2], slot = g ^ ((col>>1)&3) ----
__global__ __launch_bounds__(256) void prep_w2(const float* __restrict__ W2,
                                               _Float16* __restrict__ W2P) {
    int flat = blockIdx.x * 256 + threadIdx.x;   // (ks*4+g)*1024 + col
    int col = flat & 1023;
    int kg = flat >> 10;
    int ks = kg >> 2, g = kg & 3;
    int f = col >> 5, p = col & 31;
    half8 o;
    #pragma unroll
    for (int j = 0; j < 8; ++j) {
        int k = ks * 32 + g * 8 + j;
        float v = (p < PPF) ? W2[(size_t)k * 928 + f * PPF + p] : 0.f;
        o[j] = (_Float16)v;
    }
    size_t addr = (size_t)ks * 65536 + (size_t)(col >> 8) * 16384
                + (size_t)(col & 255) * 64 + ((g ^ ((col >> 1) & 3)) << 4);
    *(half8*)((char*)W2P + addr) = o;
}

__global__ __launch_bounds__(256) void prep_w1(const float* __restrict__ W1,
                                               _Float16* __restrict__ W1T) {
    int idx = blockIdx.x * 256 + threadIdx.x;   // 0..16383
    int n = idx >> 5, k = idx & 31;
    W1T[n * 32 + k] = (_Float16)W1[k * HID + n];
}

__global__ __launch_bounds__(256) void copy_x(const float* __restrict__ x,
                                              float* __restrict__ out) {
    const float4* xv = (const float4*)x;
    float4* ov = (float4*)out;
    int base = blockIdx.x * 1024 + threadIdx.x;
    #pragma unroll
    for (int q = 0; q < 4; ++q) ov[base + q * 256] = xv[base + q * 256];
}

__device__ __forceinline__ float softplusf(float v) {
    return fmaxf(v, 0.f) + log1pf(expf(-fabsf(v)));
}

__global__ __launch_bounds__(THREADS, 4) void flow_main(
    const float* __restrict__ x,
    const float* __restrict__ b1,
    const float* __restrict__ b2,
    const _Float16* __restrict__ W2P,
    const _Float16* __restrict__ W1T,
    float* __restrict__ out,
    float* __restrict__ ladp,
    float* __restrict__ otp)
{
    __shared__ __align__(16) char smem[SMEM_BYTES];
    const int tid = threadIdx.x;
    const int w   = tid >> 6;          // 0..7
    const int l   = tid & 63;
    const int l15 = l & 15;
    const int g   = l >> 4;            // 0..3
    const int wm  = w >> 1;            // 0..3: rows wm*32..+31
    const int nh  = w & 1;             // n-half: cols nh*128..+127
    // XCD-aware remap (4096 % 8 == 0 -> bijective)
    const int bid = (blockIdx.x & 7) * 512 + (blockIdx.x >> 3);
    const int mblk = bid >> 2, nblk = bid & 3;
    const int row0 = mblk * BM;

    const int lsw = (l15 >> 1) & 3;    // LDS slot swizzle key

    // ---- issue B chunk-0 DMA ----
    const char* gW = (const char*)W2P + (size_t)nblk * 16384 + w * 2048 + (size_t)l * 16;
    {
        char* dst = smem + STG + w * 2048;
        async_copy16(gW, dst);
        async_copy16(gW + 1024, dst + 1024);
    }

    // ---- preload b1, b2 slice ----
    ((float*)(smem + SB1))[tid] = b1[tid];
    if (tid < 232) ((float*)(smem + SB2))[tid] = b2[nblk * 232 + tid];

    // ---- x fragments (identity dims) for this wave's 32 rows ----
    half8 xf[2];
    #pragma unroll
    for (int mt = 0; mt < 2; ++mt) {
        const float4* xr = (const float4*)(x + (size_t)(row0 + wm * 32 + mt * 16 + l15) * 64 + g * 16);
        float4 q0 = xr[0], q1 = xr[1], q2 = xr[2], q3 = xr[3];
        half8 a;
        a[0] = (_Float16)q0.y; a[1] = (_Float16)q0.w;
        a[2] = (_Float16)q1.y; a[3] = (_Float16)q1.w;
        a[4] = (_Float16)q2.y; a[5] = (_Float16)q2.w;
        a[6] = (_Float16)q3.y; a[7] = (_Float16)q3.w;
        xf[mt] = a;
    }
    __syncthreads();   // chunk 0 landed; sb1/sb2 visible

    f32x4 acc[2][8];
    #pragma unroll
    for (int mt = 0; mt < 2; ++mt)
        #pragma unroll
        for (int j = 0; j < 8; ++j) acc[mt][j] = (f32x4){0.f, 0.f, 0.f, 0.f};

    char* wscr = smem + WSCR + w * 2048;
    const int bfoff = STG + (nh * 128 + l15) * 64 + ((g ^ lsw) << 4);

    for (int ks = 0; ks < NKS; ++ks) {
        // ---- GEMM1 for this k-slice: h(rows, hid ks*32..+31) in registers ----
        half8 w1f0 = *(const half8*)((const char*)W1T + (size_t)(ks * 32 + l15) * 64 + g * 16);
        half8 w1f1 = *(const half8*)((const char*)W1T + (size_t)(ks * 32 + 16 + l15) * 64 + g * 16);
        float4 bv0 = *(const float4*)(smem + SB1 + (ks * 32 + g * 4) * 4);
        float4 bv1 = *(const float4*)(smem + SB1 + (ks * 32 + 16 + g * 4) * 4);
        half8 af[2];
        #pragma unroll
        for (int mt = 0; mt < 2; ++mt) {
            f32x4 d0 = {0.f, 0.f, 0.f, 0.f}, d1 = {0.f, 0.f, 0.f, 0.f};
            d0 = __builtin_amdgcn_mfma_f32_16x16x32_f16(w1f0, xf[mt], d0, 0, 0, 0);
            d1 = __builtin_amdgcn_mfma_f32_16x16x32_f16(w1f1, xf[mt], d1, 0, 0, 0);
            // relu(d + b1), pack to fp16 pairs (k ascending within lane's 4 hid)
            unsigned p00 = pkh(fmaxf(d0[0] + bv0.x, 0.f), fmaxf(d0[1] + bv0.y, 0.f));
            unsigned p01 = pkh(fmaxf(d0[2] + bv0.z, 0.f), fmaxf(d0[3] + bv0.w, 0.f));
            unsigned p10 = pkh(fmaxf(d1[0] + bv1.x, 0.f), fmaxf(d1[1] + bv1.y, 0.f));
            unsigned p11 = pkh(fmaxf(d1[2] + bv1.z, 0.f), fmaxf(d1[3] + bv1.w, 0.f));
            // wave-private scratch: row l15, chunk = t*2+(g>>1) swizzled, half = g&1
            char* wb = wscr + mt * 1024 + l15 * 64 + (g & 1) * 8;
            *(uint2*)(wb + ((((g >> 1)) ^ lsw) << 4))     = make_uint2(p00, p01);
            *(uint2*)(wb + (((2 + (g >> 1)) ^ lsw) << 4)) = make_uint2(p10, p11);
            // A-frag for GEMM2: row = l15, k = g*8+j
            af[mt] = *(const half8*)(wscr + mt * 1024 + l15 * 64 + ((g ^ lsw) << 4));
        }

        // ---- B frags from stage ----
        half8 bf[8];
        #pragma unroll
        for (int nf = 0; nf < 8; ++nf)
            bf[nf] = *(const half8*)(smem + bfoff + nf * 1024);
        __syncthreads();               // all waves done reading stage(ks)

        if (ks < NKS - 1) {
            const char* src = gW + (size_t)(ks + 1) * 65536;
            char* dst = smem + STG + w * 2048;
            async_copy16(src, dst);
            async_copy16(src + 1024, dst + 1024);
        }
        #pragma unroll
        for (int nf = 0; nf < 8; ++nf) {
            acc[0][nf] = __builtin_amdgcn_mfma_f32_16x16x32_f16(af[0], bf[nf], acc[0][nf], 0, 0, 0);
            acc[1][nf] = __builtin_amdgcn_mfma_f32_16x16x32_f16(af[1], bf[nf], acc[1][nf], 0, 0, 0);
        }
        __syncthreads();               // DMA(ks+1) landed
    }

    // ---- epilogue: 2 passes of 64 rows ----
    const float SCALE = 0.04419417382415922f;  // 1/sqrt(512)
    #pragma unroll
    for (int pass = 0; pass < 2; ++pass) {
        if (pass == 1) __syncthreads();
        if ((wm >> 1) == pass) {
            #pragma unroll
            for (int mt = 0; mt < 2; ++mt)
                #pragma unroll
                for (int nf = 0; nf < 8; ++nf) {
                    int col = nh * 128 + nf * 16 + l15;
                    int cb = (col >> 5) * 33 + (col & 31);
                    int rb = (wm & 1) * 32 + mt * 16 + g * 4;
                    #pragma unroll
                    for (int r = 0; r < 4; ++r)
                        *(float*)(smem + OVR + ((rb + r) * PSTR + cb) * 4) = acc[mt][nf][r];
                }
        }
        __syncthreads();

        const int row_l = tid >> 3;
        const int f_l = tid & 7;
        const int grow = row0 + pass * 64 + row_l;
        const char* pb = smem + OVR + ((size_t)row_l * PSTR + (size_t)f_l * 33) * 4;
        const float* bp = (const float*)(smem + SB2) + f_l * PPF;

        // widths
        float uw[NB];
        #pragma unroll
        for (int j = 0; j < NB; ++j)
            uw[j] = (*(const float*)(pb + j * 4) + bp[j]) * SCALE;
        float mw = uw[0];
        #pragma unroll
        for (int j = 1; j < NB; ++j) mw = fmaxf(mw, uw[j]);
        float sw = 0.f;
        #pragma unroll
        for (int j = 0; j < NB; ++j) { uw[j] = expf(uw[j] - mw); sw += uw[j]; }
        float invw = 1.f / sw;
        float cw[NB + 1];
        cw[0] = -1.f;
        float cum = 0.f;
        #pragma unroll
        for (int j = 0; j < NB; ++j) {
            cum += 0.001f + 0.99f * uw[j] * invw;
            cw[j + 1] = 2.f * cum - 1.f;
        }
        cw[NB] = 1.f;

        // heights
        #pragma unroll
        for (int j = 0; j < NB; ++j)
            uw[j] = (*(const float*)(pb + (NB + j) * 4) + bp[NB + j]) * SCALE;
        float mh = uw[0];
        #pragma unroll
        for (int j = 1; j < NB; ++j) mh = fmaxf(mh, uw[j]);
        float sh = 0.f;
        #pragma unroll
        for (int j = 0; j < NB; ++j) { uw[j] = expf(uw[j] - mh); sh += uw[j]; }
        float invh = 1.f / sh;
        float ch[NB + 1];
        ch[0] = -1.f;
        float cumh = 0.f;
        #pragma unroll
        for (int j = 0; j < NB; ++j) {
            cumh += 0.001f + 0.99f * uw[j] * invh;
            ch[j + 1] = 2.f * cumh - 1.f;
        }
        ch[NB] = 1.f;

        // derivatives
        float dv[NB + 1];
        dv[0] = 1.0f;
        dv[NB] = 1.0f;
        #pragma unroll
        for (int j = 0; j < NB - 1; ++j)
            dv[j + 1] = 0.001f + softplusf(*(const float*)(pb + (2 * NB + j) * 4) + bp[2 * NB + j]);

        const int f_glob = nblk * 8 + f_l;
        const float xv = x[(size_t)grow * 64 + 2 * f_glob];
        float xc = fminf(fmaxf(xv, -1.f), 1.f);
        int idx = 0;
        #pragma unroll
        for (int j = 1; j <= NB - 1; ++j) idx += (xc >= cw[j]) ? 1 : 0;
        float in_cw = cw[0], cwn = cw[1];
        float in_ch = ch[0], chn = ch[1];
        float dk = dv[0], dk1 = dv[1];
        #pragma unroll
        for (int j = 1; j <= NB - 1; ++j) {
            bool cnd = (idx >= j);
            in_cw = cnd ? cw[j] : in_cw;
            cwn   = cnd ? cw[j + 1] : cwn;
            in_ch = cnd ? ch[j] : in_ch;
            chn   = cnd ? ch[j + 1] : chn;
            dk    = cnd ? dv[j] : dk;
            dk1   = cnd ? dv[j + 1] : dk1;
        }
        float in_w  = cwn - in_cw;
        float in_h  = chn - in_ch;
        float delta = in_h / in_w;
        float th    = (xc - in_cw) / in_w;
        float t1m   = th * (1.f - th);
        float th2   = th * th;
        float numer = in_h * (delta * th2 + dk * t1m);
        float denom = delta + (dk + dk1 - 2.f * delta) * t1m;
        float y     = in_ch + numer / denom;
        float omt   = 1.f - th;
        float dnum  = delta * delta * (dk1 * th2 + 2.f * delta * t1m + dk * omt * omt);
        float lad   = logf(dnum) - 2.f * logf(denom);

        bool inside = (xv >= -1.f) && (xv <= 1.f);
        float yo = inside ? y : xv;
        out[(size_t)grow * 64 + 2 * f_glob] = yo;
        float ladv = inside ? lad : 0.f;
        float dd = xv - yo;
        float otv = dd * dd;

        // reduce over the block's 8 features (8-lane groups)
        #pragma unroll
        for (int m = 1; m < 8; m <<= 1) {
            ladv += __shfl_xor(ladv, m);
            otv  += __shfl_xor(otv, m);
        }
        if (f_l == 0) {
            ladp[(size_t)nblk * M + grow] = ladv;
            otp[(size_t)nblk * M + grow]  = otv;
        }
    }
}

__global__ __launch_bounds__(256) void reduce_k(const float* __restrict__ ladp,
                                                const float* __restrict__ otp,
                                                float* __restrict__ lad_out,
                                                float* __restrict__ ot_out) {
    int r = blockIdx.x * 256 + threadIdx.x;
    float s = 0.f, t = 0.f;
    #pragma unroll
    for (int nb = 0; nb < NBN; ++nb) {
        s += ladp[(size_t)nb * M + r];
        t += otp[(size_t)nb * M + r];
    }
    lad_out[r] = s;
    ot_out[r]  = t;
}

extern "C" void kernel_launch(void* const* d_in, const int* in_sizes, int n_in,
                              void* d_out, int out_size, void* d_ws, size_t ws_size,
                              hipStream_t stream) {
    const float* x  = (const float*)d_in[0];
    const float* W1 = (const float*)d_in[1];
    const float* b1 = (const float*)d_in[2];
    const float* W2 = (const float*)d_in[3];
    const float* b2 = (const float*)d_in[4];
    float* out = (float*)d_out;
    float* lad = out + (size_t)M * 64;
    float* otc = lad + M;

    char* wsb = (char*)d_ws;
    _Float16* W2P = (_Float16*)(wsb + W2P_OFF);
    _Float16* W1T = (_Float16*)(wsb + W1T_OFF);
    float* ladp = (float*)(wsb + LADP_OFF);
    float* otp  = (float*)(wsb + OTP_OFF);

    hipLaunchKernelGGL(prep_w2, dim3(256), dim3(256), 0, stream, W2, W2P);
    hipLaunchKernelGGL(prep_w1, dim3(64), dim3(256), 0, stream, W1, W1T);
    hipLaunchKernelGGL(copy_x, dim3(2048), dim3(256), 0, stream, x, out);
    hipLaunchKernelGGL(flow_main, dim3(4096), dim3(THREADS), 0, stream,
                       x, b1, b2, W2P, W1T, out, ladp, otp);
    hipLaunchKernelGGL(reduce_k, dim3(512), dim3(256), 0, stream,
                       ladp, otp, lad, otc);
}